// Round 7
// baseline (12138.976 us; speedup 1.0000x reference)
//
#include <hip/hip_runtime.h>
#include <math.h>

// DCGRU encoder — both layers fused into one persistent block per batch.
// B=16 T=32 N=128 D=H=128, K=2 (M=3), L=2, 1 support.
//
// R6 post-mortem: spills fixed (VGPR 128, WRITE 2.49GB->150MB) but dur
// unchanged (~218us/stage). Cause: agent-scope grid barrier => per-XCD L2
// writeback+invalidate EVERY stage (per-XCD L2s are non-coherent, so agent
// acquire/release must wbl2/inv). FETCH 1.08GB = weights re-fetched cold
// from HBM every stage by every block; 32 CUs can't hide ~900cyc misses.
//
// This version: ZERO grid barriers in the main loop. 16 blocks; block b
// runs BOTH layers (layer1 t=s-1 first, then layer0 t=s). Handoff via LDS:
// layer0's epilogue dual-writes Y (row-major) + YT (transposed) bf16 tiles,
// which are layer1's x / xT next stage. h0/h1 in block-private global f32
// (L2-resident — and stays resident, nothing invalidates L2 anymore).
// LDS: T1+T2+T3 (work tiles) + Y + YT = 160 KB. One grid barrier after prep.
// Numerics bit-identical to the passing R6 kernel (same bf16 round points).
// Grid: 16 blocks x 512 thr (8 waves, 2/EU -> 256 regs/wave, no spills).

typedef __attribute__((ext_vector_type(8))) short bf16x8;
typedef __attribute__((ext_vector_type(4))) float f32x4;

namespace {
constexpr int GD = 16, NTHR = 512;
}

__device__ __forceinline__ unsigned short f2bf(float x) {
  unsigned u = __float_as_uint(x);
  u += 0x7fff + ((u >> 16) & 1);  // RNE
  return (unsigned short)(u >> 16);
}
__device__ __forceinline__ float bf2f(unsigned hw) {
  return __uint_as_float(hw << 16);
}
__device__ __forceinline__ unsigned pk2(float a, float b) {
  return (unsigned)f2bf(a) | ((unsigned)f2bf(b) << 16);
}
// swizzled halfword index into a [128][128] bf16 LDS tile (row stride 256B)
__device__ __forceinline__ int BIdx(int r, int c) {
  return (r << 7) + (c ^ ((r & 7) << 3));
}

// sense-reversing grid barrier — used ONCE after prep (agent-scope L2
// flush is acceptable one time; never in the main loop).
__device__ __forceinline__ void grid_barrier(unsigned* bar) {
  __syncthreads();
  if (threadIdx.x == 0) {
    unsigned* cnt = bar;
    unsigned* gen = bar + 32;
    unsigned g = __hip_atomic_load(gen, __ATOMIC_RELAXED, __HIP_MEMORY_SCOPE_AGENT);
    unsigned a = __hip_atomic_fetch_add(cnt, 1u, __ATOMIC_ACQ_REL, __HIP_MEMORY_SCOPE_AGENT);
    if (a == (unsigned)(GD - 1)) {
      __hip_atomic_store(cnt, 0u, __ATOMIC_RELAXED, __HIP_MEMORY_SCOPE_AGENT);
      __hip_atomic_fetch_add(gen, 1u, __ATOMIC_ACQ_REL, __HIP_MEMORY_SCOPE_AGENT);
    } else {
      while (__hip_atomic_load(gen, __ATOMIC_ACQUIRE, __HIP_MEMORY_SCOPE_AGENT) == g) {
        __builtin_amdgcn_s_sleep(1);
      }
    }
  }
  __syncthreads();
}

// One diffusion hop (8 waves, 32m x 64f tiles): out = S @ Bt (Bt f-major
// [f][n] in LDS). Optional Chebyshev out = 2*out - CtT[f][m] (read from the
// intact source tile). Optional f-major write (next hop's B-operand).
// Row-major write always (weight-GEMM A-chunk). Reads and writes touch
// DIFFERENT tiles -> no intra-hop sync needed.
template <bool HASCT, bool FMAJ>
__device__ __forceinline__ void diff_hop(
    const unsigned short* __restrict__ Sb, const unsigned short* Bt,
    const unsigned short* CtT, unsigned short* fmaj, unsigned short* rmaj,
    int w, int lane, int quad, int l16) {
  const int mtg = w >> 1, ftg = w & 1;
  f32x4 acc[2][4];
#pragma unroll
  for (int mi = 0; mi < 2; ++mi)
#pragma unroll
    for (int fi = 0; fi < 4; ++fi) acc[mi][fi] = (f32x4){0.f, 0.f, 0.f, 0.f};
#pragma unroll
  for (int ks = 0; ks < 4; ++ks) {
    bf16x8 a[2], bb[4];
#pragma unroll
    for (int mi = 0; mi < 2; ++mi)
      a[mi] = *(const bf16x8*)(Sb + (((mtg * 2 + mi) * 4 + ks) * 64 + lane) * 8);
#pragma unroll
    for (int fi = 0; fi < 4; ++fi)
      bb[fi] = *(const bf16x8*)(Bt + BIdx((ftg * 4 + fi) * 16 + l16, ks * 32 + quad * 8));
#pragma unroll
    for (int mi = 0; mi < 2; ++mi)
#pragma unroll
      for (int fi = 0; fi < 4; ++fi)
        acc[mi][fi] =
            __builtin_amdgcn_mfma_f32_16x16x32_bf16(a[mi], bb[fi], acc[mi][fi], 0, 0, 0);
  }
#pragma unroll
  for (int mi = 0; mi < 2; ++mi)
#pragma unroll
    for (int fi = 0; fi < 4; ++fi) {
      const int f = (ftg * 4 + fi) * 16 + l16;
      const int m0 = (mtg * 2 + mi) * 16 + quad * 4;
      float v0 = acc[mi][fi][0], v1 = acc[mi][fi][1];
      float v2 = acc[mi][fi][2], v3 = acc[mi][fi][3];
      if (HASCT) {
        const uint2 cv = *(const uint2*)(CtT + BIdx(f, m0));
        v0 = 2.f * v0 - bf2f(cv.x & 0xffffu);
        v1 = 2.f * v1 - bf2f(cv.x >> 16);
        v2 = 2.f * v2 - bf2f(cv.y & 0xffffu);
        v3 = 2.f * v3 - bf2f(cv.y >> 16);
      }
      if (FMAJ)
        *(uint2*)(fmaj + BIdx(f, m0)) = make_uint2(pk2(v0, v1), pk2(v2, v3));
      rmaj[BIdx(m0 + 0, f)] = f2bf(v0);
      rmaj[BIdx(m0 + 1, f)] = f2bf(v1);
      rmaj[BIdx(m0 + 2, f)] = f2bf(v2);
      rmaj[BIdx(m0 + 3, f)] = f2bf(v3);
    }
}

// A-fragment loaders (16x16x32 A-operand: lane l16 = row m, quad = k-group)
__device__ __forceinline__ bf16x8 afrag_rm(const unsigned short* T, int m, int k0) {
  return *(const bf16x8*)(T + BIdx(m, k0));
}
__device__ __forceinline__ bf16x8 afrag_G(const float* __restrict__ g, int m, int k0) {
  const float4 v0 = *(const float4*)(g + m * 128 + k0);
  const float4 v1 = *(const float4*)(g + m * 128 + k0 + 4);
  bf16x8 a;
  a[0] = (short)f2bf(v0.x); a[1] = (short)f2bf(v0.y);
  a[2] = (short)f2bf(v0.z); a[3] = (short)f2bf(v0.w);
  a[4] = (short)f2bf(v1.x); a[5] = (short)f2bf(v1.y);
  a[6] = (short)f2bf(v1.z); a[7] = (short)f2bf(v1.w);
  return a;
}

// build transposed bf16 tile (BIdx layout) from row-major f32 source:
// coalesced global reads + scattered LDS writes.
__device__ __forceinline__ void buildT_f32(const float* __restrict__ src,
                                           unsigned short* T, int tid) {
  const int row = tid >> 2, cb = (tid & 3) << 5;
#pragma unroll
  for (int j = 0; j < 8; ++j) {
    const float4 v = *(const float4*)(src + row * 128 + cb + j * 4);
    T[BIdx(cb + j * 4 + 0, row)] = f2bf(v.x);
    T[BIdx(cb + j * 4 + 1, row)] = f2bf(v.y);
    T[BIdx(cb + j * 4 + 2, row)] = f2bf(v.z);
    T[BIdx(cb + j * 4 + 3, row)] = f2bf(v.w);
  }
}

// weight-GEMM accumulate for one k-chunk c. af[mi][ks] prepared by caller.
__device__ __forceinline__ void gemm_gates(const bf16x8 (&af)[2][4],
    const unsigned short* __restrict__ WgL, int c, int ow, int lane,
    f32x4 (&accg)[2][8]) {
#pragma unroll
  for (int ks = 0; ks < 4; ++ks)
#pragma unroll
    for (int of = 0; of < 8; ++of) {
      const int ot = (of < 4) ? (ow * 4 + of) : (4 + ow * 4 + of);  // u-half -> ot 8..15
      const bf16x8 bb =
          *(const bf16x8*)(WgL + ((long)(ot * 24 + c * 4 + ks)) * 512 + (long)lane * 8);
      accg[0][of] = __builtin_amdgcn_mfma_f32_16x16x32_bf16(af[0][ks], bb, accg[0][of], 0, 0, 0);
      accg[1][of] = __builtin_amdgcn_mfma_f32_16x16x32_bf16(af[1][ks], bb, accg[1][of], 0, 0, 0);
    }
}
__device__ __forceinline__ void gemm_cand(const bf16x8 (&af)[2][4],
    const unsigned short* __restrict__ WcL, int c, int ow, int lane,
    f32x4 (&accc)[2][4]) {
#pragma unroll
  for (int ks = 0; ks < 4; ++ks)
#pragma unroll
    for (int of = 0; of < 4; ++of) {
      const int ot = ow * 4 + of;
      const bf16x8 bb =
          *(const bf16x8*)(WcL + ((long)(ot * 24 + c * 4 + ks)) * 512 + (long)lane * 8);
      accc[0][of] = __builtin_amdgcn_mfma_f32_16x16x32_bf16(af[0][ks], bb, accc[0][of], 0, 0, 0);
      accc[1][of] = __builtin_amdgcn_mfma_f32_16x16x32_bf16(af[1][ks], bb, accc[1][of], 0, 0, 0);
    }
}

// One full DCGRU timestep for one layer, entirely within the block.
// LAYER==0: x from global inputs; writes Y/YT (handoff) + out finals.
// LAYER==1: x = Y/YT in LDS; writes out sequence + finals.
template <int LAYER>
__device__ __forceinline__ void step(
    int t, int b, const float* __restrict__ inputs,
    float* __restrict__ hL, const unsigned short* __restrict__ Sb,
    const unsigned short* __restrict__ WgL, const unsigned short* __restrict__ WcL,
    const float* __restrict__ bgL, const float* __restrict__ bcL,
    float* __restrict__ out,
    unsigned short* T1, unsigned short* T2, unsigned short* T3,
    unsigned short* Y, unsigned short* YT,
    int tid, int w, int lane, int quad, int l16, int mw, int ow) {
  const float* xsrc = inputs + (long)(b * 32 + t) * 16384;  // LAYER==0 only

  f32x4 accg[2][8], accc[2][4];
#pragma unroll
  for (int mi = 0; mi < 2; ++mi) {
#pragma unroll
    for (int of = 0; of < 8; ++of) accg[mi][of] = (f32x4){0.f, 0.f, 0.f, 0.f};
#pragma unroll
    for (int of = 0; of < 4; ++of) accc[mi][of] = (f32x4){0.f, 0.f, 0.f, 0.f};
  }
  bf16x8 af[2][4];

  // ---- phase A: x | D1x | D2x (chunks 0/2/4 of both GEMMs) ----
  if (LAYER == 0) buildT_f32(xsrc, T1, tid);  // xT -> T1
  __syncthreads();
  const unsigned short* XT = (LAYER == 0) ? T1 : YT;
  diff_hop<false, true>(Sb, XT, nullptr, T2, T3, w, lane, quad, l16);  // D1
  __syncthreads();
  // GEMM c0 (x) + c2 (D1 in T3)
#pragma unroll
  for (int mi = 0; mi < 2; ++mi)
#pragma unroll
    for (int ks = 0; ks < 4; ++ks) {
      const int m = mw * 32 + mi * 16 + l16, k0 = ks * 32 + quad * 8;
      af[mi][ks] = (LAYER == 0) ? afrag_G(xsrc, m, k0) : afrag_rm(Y, m, k0);
    }
  gemm_gates(af, WgL, 0, ow, lane, accg);
  gemm_cand(af, WcL, 0, ow, lane, accc);
#pragma unroll
  for (int mi = 0; mi < 2; ++mi)
#pragma unroll
    for (int ks = 0; ks < 4; ++ks)
      af[mi][ks] = afrag_rm(T3, mw * 32 + mi * 16 + l16, ks * 32 + quad * 8);
  gemm_gates(af, WgL, 2, ow, lane, accg);
  gemm_cand(af, WcL, 2, ow, lane, accc);
  __syncthreads();
  diff_hop<true, false>(Sb, T2, XT, nullptr, T3, w, lane, quad, l16);  // D2
  __syncthreads();
  // GEMM c4 (D2 in T3) + build hT -> T1 (disjoint tiles)
#pragma unroll
  for (int mi = 0; mi < 2; ++mi)
#pragma unroll
    for (int ks = 0; ks < 4; ++ks)
      af[mi][ks] = afrag_rm(T3, mw * 32 + mi * 16 + l16, ks * 32 + quad * 8);
  gemm_gates(af, WgL, 4, ow, lane, accg);
  gemm_cand(af, WcL, 4, ow, lane, accc);
  buildT_f32(hL, T1, tid);
  __syncthreads();

  // ---- phase B: h | D1h | D2h (gates chunks 1/3/5) ----
  diff_hop<false, true>(Sb, T1, nullptr, T2, T3, w, lane, quad, l16);
  __syncthreads();
#pragma unroll
  for (int mi = 0; mi < 2; ++mi)
#pragma unroll
    for (int ks = 0; ks < 4; ++ks)
      af[mi][ks] = afrag_G(hL, mw * 32 + mi * 16 + l16, ks * 32 + quad * 8);
  gemm_gates(af, WgL, 1, ow, lane, accg);
#pragma unroll
  for (int mi = 0; mi < 2; ++mi)
#pragma unroll
    for (int ks = 0; ks < 4; ++ks)
      af[mi][ks] = afrag_rm(T3, mw * 32 + mi * 16 + l16, ks * 32 + quad * 8);
  gemm_gates(af, WgL, 3, ow, lane, accg);
  __syncthreads();
  diff_hop<true, false>(Sb, T2, T1, nullptr, T3, w, lane, quad, l16);
  __syncthreads();
#pragma unroll
  for (int mi = 0; mi < 2; ++mi)
#pragma unroll
    for (int ks = 0; ks < 4; ++ks)
      af[mi][ks] = afrag_rm(T3, mw * 32 + mi * 16 + l16, ks * 32 + quad * 8);
  gemm_gates(af, WgL, 5, ow, lane, accg);
  // gates epilogue: r -> rh (rhT in T1, rh rows in T2); u stays in accg[*][4..7]
#pragma unroll
  for (int mi = 0; mi < 2; ++mi) {
#pragma unroll
    for (int of = 0; of < 4; ++of) {
      const int o = ow * 64 + of * 16 + l16;
      const float bias = bgL[o];
      const int m0 = mw * 32 + mi * 16 + quad * 4;
      float rh[4];
#pragma unroll
      for (int r = 0; r < 4; ++r) {
        const float g = 1.f / (1.f + __expf(-(accg[mi][of][r] + bias)));
        rh[r] = g * hL[(m0 + r) * 128 + o];
      }
      *(uint2*)(T1 + BIdx(o, m0)) = make_uint2(pk2(rh[0], rh[1]), pk2(rh[2], rh[3]));
      T2[BIdx(m0 + 0, o)] = f2bf(rh[0]);
      T2[BIdx(m0 + 1, o)] = f2bf(rh[1]);
      T2[BIdx(m0 + 2, o)] = f2bf(rh[2]);
      T2[BIdx(m0 + 3, o)] = f2bf(rh[3]);
    }
#pragma unroll
    for (int of = 4; of < 8; ++of) {
      const int o = 128 + ow * 64 + (of - 4) * 16 + l16;
      const float bias = bgL[o];
#pragma unroll
      for (int r = 0; r < 4; ++r)
        accg[mi][of][r] = 1.f / (1.f + __expf(-(accg[mi][of][r] + bias)));
    }
  }
  __syncthreads();

  // ---- phase C: rh | D1rh | D2rh (candidate chunks 1/3/5) ----
#pragma unroll
  for (int mi = 0; mi < 2; ++mi)
#pragma unroll
    for (int ks = 0; ks < 4; ++ks)
      af[mi][ks] = afrag_rm(T2, mw * 32 + mi * 16 + l16, ks * 32 + quad * 8);
  gemm_cand(af, WcL, 1, ow, lane, accc);
  __syncthreads();
  diff_hop<false, true>(Sb, T1, nullptr, T2, T3, w, lane, quad, l16);
  __syncthreads();
#pragma unroll
  for (int mi = 0; mi < 2; ++mi)
#pragma unroll
    for (int ks = 0; ks < 4; ++ks)
      af[mi][ks] = afrag_rm(T3, mw * 32 + mi * 16 + l16, ks * 32 + quad * 8);
  gemm_cand(af, WcL, 3, ow, lane, accc);
  __syncthreads();
  diff_hop<true, false>(Sb, T2, T1, nullptr, T3, w, lane, quad, l16);
  __syncthreads();
#pragma unroll
  for (int mi = 0; mi < 2; ++mi)
#pragma unroll
    for (int ks = 0; ks < 4; ++ks)
      af[mi][ks] = afrag_rm(T3, mw * 32 + mi * 16 + l16, ks * 32 + quad * 8);
  gemm_cand(af, WcL, 5, ow, lane, accc);
  // final epilogue: c = tanh(acc_c + bc); h' = u*h + (1-u)*c
#pragma unroll
  for (int mi = 0; mi < 2; ++mi)
#pragma unroll
    for (int of = 0; of < 4; ++of) {
      const int o = ow * 64 + of * 16 + l16;
      const float bias = bcL[o];
#pragma unroll
      for (int r = 0; r < 4; ++r) {
        const int mm = mw * 32 + mi * 16 + quad * 4 + r;
        const float cv = tanhf(accc[mi][of][r] + bias);
        const float uv = accg[mi][4 + of][r];
        const float hv = hL[mm * 128 + o];
        const float hn = uv * hv + (1.f - uv) * cv;
        hL[mm * 128 + o] = hn;
        const long base = (long)(b * 128 + mm) * 128 + o;
        if (LAYER == 0) {
          Y[BIdx(mm, o)] = f2bf(hn);   // layer1's x (row-major)
          YT[BIdx(o, mm)] = f2bf(hn);  // layer1's xT (hop B-operand)
          if (t == 31) out[base] = hn;
        } else {
          out[524288 + (long)t * 262144 + base] = hn;
          if (t == 31) out[262144 + base] = hn;
        }
      }
    }
  __syncthreads();
}

__global__ void __launch_bounds__(NTHR, 2) dcgru(
    const float* __restrict__ inputs, const float* __restrict__ init_h,
    const float* __restrict__ sup,
    const float* __restrict__ Wg0, const float* __restrict__ bg0,
    const float* __restrict__ Wc0, const float* __restrict__ bc0,
    const float* __restrict__ Wg1, const float* __restrict__ bg1,
    const float* __restrict__ Wc1, const float* __restrict__ bc1,
    float* __restrict__ out, void* __restrict__ wsv) {
  __shared__ unsigned short T1[16384];  // 32 KB work tile
  __shared__ unsigned short T2[16384];  // 32 KB work tile
  __shared__ unsigned short T3[16384];  // 32 KB work tile
  __shared__ unsigned short Y[16384];   // 32 KB layer0->layer1 x (row-major)
  __shared__ unsigned short YT[16384];  // 32 KB layer0->layer1 xT

  unsigned* bar = (unsigned*)wsv;
  float* h_ws = (float*)wsv + 64;                          // [16][2][128][128]
  unsigned short* Sfr = (unsigned short*)(h_ws + 524288);  // [32][8][4][64][8]
  unsigned short* Wbg = Sfr + 524288;                      // [2][16][24][64][8]
  unsigned short* Wbc = Wbg + 393216;                      // [2][8][24][64][8]

  const int tid = threadIdx.x, bid = blockIdx.x;
  const int gtid = bid * NTHR + tid, gstride = GD * NTHR;
  const int lane = tid & 63, w = tid >> 6, quad = lane >> 4, l16 = lane & 15;
  const int b = bid;
  const int mw = w >> 1, ow = w & 1;  // GEMM tiling: wave = 32m x 64o

  // ---- prep: h -> workspace; S/W fragment pre-arrangement (bf16) ----
  for (int i = tid; i < 32768; i += NTHR) {
    const int layer = i >> 14, j = i & 16383;
    h_ws[(long)(b * 2 + layer) * 16384 + j] = init_h[(long)(layer * 16 + b) * 16384 + j];
  }
  for (int idx = gtid; idx < 65536; idx += gstride) {  // S frags
    const int tt = idx >> 11, mt = (idx >> 8) & 7, ks = (idx >> 6) & 3, ln = idx & 63;
    const int m = mt * 16 + (ln & 15), k0 = ks * 32 + (ln >> 4) * 8;
    const float* src = sup + (long)tt * 16384 + m * 128 + k0;
    bf16x8 v;
#pragma unroll
    for (int j = 0; j < 8; j++) v[j] = (short)f2bf(src[j]);
    *(bf16x8*)(Sfr + (long)idx * 8) = v;
  }
  for (int idx = gtid; idx < 49152; idx += gstride) {  // Wg frags (2x16x24x64)
    const int l = idx / 24576;
    int rem = idx - l * 24576;
    const int ot = rem / 1536; rem -= ot * 1536;
    const int ks = rem >> 6, ln = rem & 63;
    const int o = ot * 16 + (ln & 15);
    const float* W = l ? Wg1 : Wg0;
    bf16x8 v;
#pragma unroll
    for (int j = 0; j < 8; j++) {
      const int kk = ks * 32 + (ln >> 4) * 8 + j;
      const int mm = kk >> 8, d = kk & 255;  // row reorder (d*3+mm) -> k
      v[j] = (short)f2bf(W[(d * 3 + mm) * 256 + o]);
    }
    *(bf16x8*)(Wbg + (long)idx * 8) = v;
  }
  for (int idx = gtid; idx < 24576; idx += gstride) {  // Wc frags (2x8x24x64)
    const int l = idx / 12288;
    int rem = idx - l * 12288;
    const int ot = rem / 1536; rem -= ot * 1536;
    const int ks = rem >> 6, ln = rem & 63;
    const int o = ot * 16 + (ln & 15);
    const float* W = l ? Wc1 : Wc0;
    bf16x8 v;
#pragma unroll
    for (int j = 0; j < 8; j++) {
      const int kk = ks * 32 + (ln >> 4) * 8 + j;
      const int mm = kk >> 8, d = kk & 255;
      v[j] = (short)f2bf(W[(d * 3 + mm) * 128 + o]);
    }
    *(bf16x8*)(Wbc + (long)idx * 8) = v;
  }
  grid_barrier(bar);  // one-time: S/W frags visible to all blocks

  float* h0 = h_ws + (long)(b * 2 + 0) * 16384;
  float* h1 = h_ws + (long)(b * 2 + 1) * 16384;
  const unsigned short* Wg0f = Wbg;
  const unsigned short* Wg1f = Wbg + (long)16 * 24 * 512;
  const unsigned short* Wc0f = Wbc;
  const unsigned short* Wc1f = Wbc + (long)8 * 24 * 512;

  // ---- main loop: layer1 (t=s-1) first, then layer0 (t=s). No grid sync. ----
  for (int s = 0; s <= 32; ++s) {
    if (s >= 1)
      step<1>(s - 1, b, inputs, h1, Sfr + (long)(s - 1) * 16384, Wg1f, Wc1f,
              bg1, bc1, out, T1, T2, T3, Y, YT, tid, w, lane, quad, l16, mw, ow);
    if (s < 32)
      step<0>(s, b, inputs, h0, Sfr + (long)s * 16384, Wg0f, Wc0f,
              bg0, bc0, out, T1, T2, T3, Y, YT, tid, w, lane, quad, l16, mw, ow);
  }
}

extern "C" void kernel_launch(void* const* d_in, const int* in_sizes, int n_in,
                              void* d_out, int out_size, void* d_ws, size_t ws_size,
                              hipStream_t stream) {
  const float* inputs = (const float*)d_in[0];
  const float* init_h = (const float*)d_in[1];
  const float* sup    = (const float*)d_in[2];
  const float* Wg0 = (const float*)d_in[3];
  const float* bg0 = (const float*)d_in[4];
  const float* Wc0 = (const float*)d_in[5];
  const float* bc0 = (const float*)d_in[6];
  const float* Wg1 = (const float*)d_in[7];
  const float* bg1 = (const float*)d_in[8];
  const float* Wc1 = (const float*)d_in[9];
  const float* bc1 = (const float*)d_in[10];
  float* out = (float*)d_out;

  hipMemsetAsync(d_ws, 0, 256, stream);  // zero barrier state
  dcgru<<<GD, NTHR, 0, stream>>>(inputs, init_h, sup, Wg0, bg0, Wc0, bc0,
                                 Wg1, bg1, Wc1, bc1, out, d_ws);
}

// Round 13
// 8128.489 us; speedup vs baseline: 1.4934x; 1.4934x over previous
//
#include <hip/hip_runtime.h>
#include <math.h>

// DCGRU encoder — both layers fused per-batch persistent blocks, latency-
// oriented retile. B=16 T=32 N=128 D=H=128, K=2 (M=3), L=2, 1 support.
//
// R7 post-mortem: removing grid barriers changed nothing (~190us/step,
// MfmaUtil 0.3%) -> bottleneck is the serialized VMEM chain: 288 weight-frag
// loads/wave/step, each feeding ONE MFMA, ~700cy each, ~8 in flight.
// This version: retile for fragment reuse.
//   GEMMs: wave = all 128 m x o-slice (gates ot=w*2+oj, cand ot=w).
//     Per chunk: preload 12 B-frags -> 96 MFMAs. 72 weight loads/wave/step,
//     each reused 8x (was 288 reused 1x).
//   Diffusion: wave = m-slice (mt=w) x all f. 4 S-frag loads/hop, reused 8x.
//   u-gate moves to LDS f32 buffer U (aliases Ybuf: x-staging dead after
//   phase A; u lives B-epilogue -> final epilogue; handoff Y/YT written
//   after a sync). x staged once into Y/YT -> c0 A-frags from LDS.
// FP accumulation order per output unchanged -> absmax bit-identical.
// Grid: 16 blocks x 512 thr (8 waves, 2/EU, 256 reg budget), 160KB LDS,
// zero grid barriers in main loop.

typedef __attribute__((ext_vector_type(8))) short bf16x8;
typedef __attribute__((ext_vector_type(4))) float f32x4;

namespace {
constexpr int GD = 16, NTHR = 512;
}

__device__ __forceinline__ unsigned short f2bf(float x) {
  unsigned u = __float_as_uint(x);
  u += 0x7fff + ((u >> 16) & 1);  // RNE
  return (unsigned short)(u >> 16);
}
__device__ __forceinline__ float bf2f(unsigned hw) {
  return __uint_as_float(hw << 16);
}
__device__ __forceinline__ unsigned pk2(float a, float b) {
  return (unsigned)f2bf(a) | ((unsigned)f2bf(b) << 16);
}
// swizzled halfword index into a [128][128] bf16 LDS tile (row stride 256B)
__device__ __forceinline__ int BIdx(int r, int c) {
  return (r << 7) + (c ^ ((r & 7) << 3));
}
// swizzled f32 index into U [128 m][128 o] (bank-conflict-free col access)
__device__ __forceinline__ int UIdx(int m, int o) {
  return (m << 7) + (o ^ ((m & 7) << 2));
}
__device__ __forceinline__ f32x4 MF(bf16x8 a, bf16x8 b, f32x4 c) {
  return __builtin_amdgcn_mfma_f32_16x16x32_bf16(a, b, c, 0, 0, 0);
}

// grid barrier — used ONCE after prep
__device__ __forceinline__ void grid_barrier(unsigned* bar) {
  __syncthreads();
  if (threadIdx.x == 0) {
    unsigned* cnt = bar;
    unsigned* gen = bar + 32;
    unsigned g = __hip_atomic_load(gen, __ATOMIC_RELAXED, __HIP_MEMORY_SCOPE_AGENT);
    unsigned a = __hip_atomic_fetch_add(cnt, 1u, __ATOMIC_ACQ_REL, __HIP_MEMORY_SCOPE_AGENT);
    if (a == (unsigned)(GD - 1)) {
      __hip_atomic_store(cnt, 0u, __ATOMIC_RELAXED, __HIP_MEMORY_SCOPE_AGENT);
      __hip_atomic_fetch_add(gen, 1u, __ATOMIC_ACQ_REL, __HIP_MEMORY_SCOPE_AGENT);
    } else {
      while (__hip_atomic_load(gen, __ATOMIC_ACQUIRE, __HIP_MEMORY_SCOPE_AGENT) == g) {
        __builtin_amdgcn_s_sleep(1);
      }
    }
  }
  __syncthreads();
}

// A-fragment loaders (16x16x32 A-operand: lane l16 = row m, quad = k-group)
__device__ __forceinline__ bf16x8 afrag_rm(const unsigned short* T, int m, int k0) {
  return *(const bf16x8*)(T + BIdx(m, k0));
}
__device__ __forceinline__ bf16x8 afrag_G(const float* __restrict__ g, int m, int k0) {
  const float4 v0 = *(const float4*)(g + m * 128 + k0);
  const float4 v1 = *(const float4*)(g + m * 128 + k0 + 4);
  bf16x8 a;
  a[0] = (short)f2bf(v0.x); a[1] = (short)f2bf(v0.y);
  a[2] = (short)f2bf(v0.z); a[3] = (short)f2bf(v0.w);
  a[4] = (short)f2bf(v1.x); a[5] = (short)f2bf(v1.y);
  a[6] = (short)f2bf(v1.z); a[7] = (short)f2bf(v1.w);
  return a;
}

// build transposed bf16 tile from row-major f32 source (hT at A5)
__device__ __forceinline__ void buildT_f32(const float* __restrict__ src,
                                           unsigned short* T, int tid) {
  const int row = tid >> 2, cb = (tid & 3) << 5;
#pragma unroll
  for (int j = 0; j < 8; ++j) {
    const float4 v = *(const float4*)(src + row * 128 + cb + j * 4);
    T[BIdx(cb + j * 4 + 0, row)] = f2bf(v.x);
    T[BIdx(cb + j * 4 + 1, row)] = f2bf(v.y);
    T[BIdx(cb + j * 4 + 2, row)] = f2bf(v.z);
    T[BIdx(cb + j * 4 + 3, row)] = f2bf(v.w);
  }
}

// One diffusion hop: wave w owns m-rows [w*16, w*16+16), all 128 f.
// Preload 4 S-frags (VMEM), then 32 MFMAs with LDS B-frags (8x reuse).
template <bool HASCT, bool FMAJ>
__device__ __forceinline__ void diff_hop(
    const unsigned short* __restrict__ Sb, const unsigned short* Bt,
    const unsigned short* CtT, unsigned short* fmaj, unsigned short* rmaj,
    int w, int lane, int quad, int l16) {
  bf16x8 a[4];
#pragma unroll
  for (int ks = 0; ks < 4; ++ks)
    a[ks] = *(const bf16x8*)(Sb + (((w * 4 + ks) * 64) + lane) * 8);
  f32x4 acc[8];
#pragma unroll
  for (int fi = 0; fi < 8; ++fi) acc[fi] = (f32x4){0.f, 0.f, 0.f, 0.f};
#pragma unroll
  for (int fi = 0; fi < 8; ++fi)
#pragma unroll
    for (int ks = 0; ks < 4; ++ks) {
      const bf16x8 bb =
          *(const bf16x8*)(Bt + BIdx(fi * 16 + l16, ks * 32 + quad * 8));
      acc[fi] = MF(a[ks], bb, acc[fi]);
    }
#pragma unroll
  for (int fi = 0; fi < 8; ++fi) {
    const int f = fi * 16 + l16;
    const int m0 = w * 16 + quad * 4;
    float v0 = acc[fi][0], v1 = acc[fi][1], v2 = acc[fi][2], v3 = acc[fi][3];
    if (HASCT) {
      const uint2 cv = *(const uint2*)(CtT + BIdx(f, m0));
      v0 = 2.f * v0 - bf2f(cv.x & 0xffffu);
      v1 = 2.f * v1 - bf2f(cv.x >> 16);
      v2 = 2.f * v2 - bf2f(cv.y & 0xffffu);
      v3 = 2.f * v3 - bf2f(cv.y >> 16);
    }
    if (FMAJ)
      *(uint2*)(fmaj + BIdx(f, m0)) = make_uint2(pk2(v0, v1), pk2(v2, v3));
    rmaj[BIdx(m0 + 0, f)] = f2bf(v0);
    rmaj[BIdx(m0 + 1, f)] = f2bf(v1);
    rmaj[BIdx(m0 + 2, f)] = f2bf(v2);
    rmaj[BIdx(m0 + 3, f)] = f2bf(v3);
  }
}

// combined gates+cand chunk (phase A): preload 12 B-frags, 96 MFMAs
__device__ __forceinline__ void gemmA(
    const unsigned short* A, const unsigned short* __restrict__ WgL,
    const unsigned short* __restrict__ WcL, int c,
    int w, int lane, int quad, int l16, f32x4 (&accg)[8][2], f32x4 (&accc)[8]) {
  bf16x8 bg0[4], bg1[4], bc[4];
#pragma unroll
  for (int ks = 0; ks < 4; ++ks) {
    bg0[ks] = *(const bf16x8*)(WgL + ((long)((w * 2 + 0) * 24 + c * 4 + ks)) * 512 + (long)lane * 8);
    bg1[ks] = *(const bf16x8*)(WgL + ((long)((w * 2 + 1) * 24 + c * 4 + ks)) * 512 + (long)lane * 8);
    bc[ks]  = *(const bf16x8*)(WcL + ((long)(w * 24 + c * 4 + ks)) * 512 + (long)lane * 8);
  }
#pragma unroll
  for (int mt = 0; mt < 8; ++mt)
#pragma unroll
    for (int ks = 0; ks < 4; ++ks) {
      const bf16x8 a = afrag_rm(A, mt * 16 + l16, ks * 32 + quad * 8);
      accg[mt][0] = MF(a, bg0[ks], accg[mt][0]);
      accg[mt][1] = MF(a, bg1[ks], accg[mt][1]);
      accc[mt]    = MF(a, bc[ks], accc[mt]);
    }
}
// gates-only chunk, A from LDS rmaj
__device__ __forceinline__ void gemmG_rm(
    const unsigned short* A, const unsigned short* __restrict__ WgL, int c,
    int w, int lane, int quad, int l16, f32x4 (&accg)[8][2]) {
  bf16x8 bg0[4], bg1[4];
#pragma unroll
  for (int ks = 0; ks < 4; ++ks) {
    bg0[ks] = *(const bf16x8*)(WgL + ((long)((w * 2 + 0) * 24 + c * 4 + ks)) * 512 + (long)lane * 8);
    bg1[ks] = *(const bf16x8*)(WgL + ((long)((w * 2 + 1) * 24 + c * 4 + ks)) * 512 + (long)lane * 8);
  }
#pragma unroll
  for (int mt = 0; mt < 8; ++mt)
#pragma unroll
    for (int ks = 0; ks < 4; ++ks) {
      const bf16x8 a = afrag_rm(A, mt * 16 + l16, ks * 32 + quad * 8);
      accg[mt][0] = MF(a, bg0[ks], accg[mt][0]);
      accg[mt][1] = MF(a, bg1[ks], accg[mt][1]);
    }
}
// gates-only chunk, A from global f32 (h)
__device__ __forceinline__ void gemmG_h(
    const float* __restrict__ hL, const unsigned short* __restrict__ WgL, int c,
    int w, int lane, int quad, int l16, f32x4 (&accg)[8][2]) {
  bf16x8 bg0[4], bg1[4];
#pragma unroll
  for (int ks = 0; ks < 4; ++ks) {
    bg0[ks] = *(const bf16x8*)(WgL + ((long)((w * 2 + 0) * 24 + c * 4 + ks)) * 512 + (long)lane * 8);
    bg1[ks] = *(const bf16x8*)(WgL + ((long)((w * 2 + 1) * 24 + c * 4 + ks)) * 512 + (long)lane * 8);
  }
#pragma unroll
  for (int mt = 0; mt < 8; ++mt)
#pragma unroll
    for (int ks = 0; ks < 4; ++ks) {
      const bf16x8 a = afrag_G(hL, mt * 16 + l16, ks * 32 + quad * 8);
      accg[mt][0] = MF(a, bg0[ks], accg[mt][0]);
      accg[mt][1] = MF(a, bg1[ks], accg[mt][1]);
    }
}
// cand-only chunk, A from LDS rmaj
__device__ __forceinline__ void gemmC_rm(
    const unsigned short* A, const unsigned short* __restrict__ WcL, int c,
    int w, int lane, int quad, int l16, f32x4 (&accc)[8]) {
  bf16x8 bc[4];
#pragma unroll
  for (int ks = 0; ks < 4; ++ks)
    bc[ks] = *(const bf16x8*)(WcL + ((long)(w * 24 + c * 4 + ks)) * 512 + (long)lane * 8);
#pragma unroll
  for (int mt = 0; mt < 8; ++mt)
#pragma unroll
    for (int ks = 0; ks < 4; ++ks) {
      const bf16x8 a = afrag_rm(A, mt * 16 + l16, ks * 32 + quad * 8);
      accc[mt] = MF(a, bc[ks], accc[mt]);
    }
}

// One full DCGRU timestep for one layer, entirely within the block.
template <int LAYER>
__device__ __forceinline__ void step(
    int t, int b, const float* __restrict__ inputs,
    float* __restrict__ hL, const unsigned short* __restrict__ Sb,
    const unsigned short* __restrict__ WgL, const unsigned short* __restrict__ WcL,
    const float* __restrict__ bgL, const float* __restrict__ bcL,
    float* __restrict__ out,
    unsigned short* T1, unsigned short* T2, unsigned short* T3,
    unsigned short* Y, unsigned short* YT, float* U,
    int tid, int w, int lane, int quad, int l16) {
  f32x4 accg[8][2];
  f32x4 accc[8];
#pragma unroll
  for (int mt = 0; mt < 8; ++mt) {
    accg[mt][0] = (f32x4){0.f, 0.f, 0.f, 0.f};
    accg[mt][1] = (f32x4){0.f, 0.f, 0.f, 0.f};
    accc[mt] = (f32x4){0.f, 0.f, 0.f, 0.f};
  }

  // ---- phase A: x | D1x | D2x (chunks 0/2/4, gates+cand) ----
  if (LAYER == 0) {  // stage x into Y (rmaj bf16) + YT (transposed)
    const float* xsrc = inputs + (long)(b * 32 + t) * 16384;
    const int row = tid >> 2, cb = (tid & 3) << 5;
#pragma unroll
    for (int j = 0; j < 8; ++j) {
      const float4 v = *(const float4*)(xsrc + row * 128 + cb + j * 4);
      *(uint2*)(Y + BIdx(row, cb + j * 4)) =
          make_uint2(pk2(v.x, v.y), pk2(v.z, v.w));
      YT[BIdx(cb + j * 4 + 0, row)] = f2bf(v.x);
      YT[BIdx(cb + j * 4 + 1, row)] = f2bf(v.y);
      YT[BIdx(cb + j * 4 + 2, row)] = f2bf(v.z);
      YT[BIdx(cb + j * 4 + 3, row)] = f2bf(v.w);
    }
  }
  __syncthreads();
  diff_hop<false, true>(Sb, YT, nullptr, T2, T3, w, lane, quad, l16);  // D1x
  __syncthreads();
  gemmA(Y, WgL, WcL, 0, w, lane, quad, l16, accg, accc);   // c0 (x)
  gemmA(T3, WgL, WcL, 2, w, lane, quad, l16, accg, accc);  // c2 (D1x)
  __syncthreads();
  diff_hop<true, false>(Sb, T2, YT, nullptr, T3, w, lane, quad, l16);  // D2x
  __syncthreads();
  gemmA(T3, WgL, WcL, 4, w, lane, quad, l16, accg, accc);  // c4 (D2x)
  buildT_f32(hL, T1, tid);                                 // hT -> T1
  __syncthreads();

  // ---- phase B: h | D1h | D2h (gates chunks 1/3/5) ----
  diff_hop<false, true>(Sb, T1, nullptr, T2, T3, w, lane, quad, l16);  // D1h
  __syncthreads();
  gemmG_h(hL, WgL, 1, w, lane, quad, l16, accg);           // c1 (h)
  gemmG_rm(T3, WgL, 3, w, lane, quad, l16, accg);          // c3 (D1h)
  __syncthreads();
  diff_hop<true, false>(Sb, T2, T1, nullptr, T3, w, lane, quad, l16);  // D2h
  __syncthreads();
  gemmG_rm(T3, WgL, 5, w, lane, quad, l16, accg);          // c5 (D2h)
  // gates epilogue: waves 0-3 r -> rh (rhT T1, rmaj T2); waves 4-7 u -> U
  if (w < 4) {
#pragma unroll
    for (int mt = 0; mt < 8; ++mt)
#pragma unroll
      for (int oj = 0; oj < 2; ++oj) {
        const int o = w * 32 + oj * 16 + l16;
        const float bias = bgL[o];
        const int m0 = mt * 16 + quad * 4;
        float rh[4];
#pragma unroll
        for (int r = 0; r < 4; ++r) {
          const float g = 1.f / (1.f + __expf(-(accg[mt][oj][r] + bias)));
          rh[r] = g * hL[(m0 + r) * 128 + o];
        }
        *(uint2*)(T1 + BIdx(o, m0)) =
            make_uint2(pk2(rh[0], rh[1]), pk2(rh[2], rh[3]));
        T2[BIdx(m0 + 0, o)] = f2bf(rh[0]);
        T2[BIdx(m0 + 1, o)] = f2bf(rh[1]);
        T2[BIdx(m0 + 2, o)] = f2bf(rh[2]);
        T2[BIdx(m0 + 3, o)] = f2bf(rh[3]);
      }
  } else {
#pragma unroll
    for (int mt = 0; mt < 8; ++mt)
#pragma unroll
      for (int oj = 0; oj < 2; ++oj) {
        const int o = w * 32 + oj * 16 + l16;  // in [128,256)
        const float bias = bgL[o];
        const int m0 = mt * 16 + quad * 4;
#pragma unroll
        for (int r = 0; r < 4; ++r)
          U[UIdx(m0 + r, o - 128)] =
              1.f / (1.f + __expf(-(accg[mt][oj][r] + bias)));
      }
  }
  __syncthreads();

  // ---- phase C: rh | D1rh | D2rh (candidate chunks 1/3/5) ----
  gemmC_rm(T2, WcL, 1, w, lane, quad, l16, accc);          // c1 (rh)
  __syncthreads();
  diff_hop<false, true>(Sb, T1, nullptr, T2, T3, w, lane, quad, l16);  // D1rh
  __syncthreads();
  gemmC_rm(T3, WcL, 3, w, lane, quad, l16, accc);          // c3 (D1rh)
  __syncthreads();
  diff_hop<true, false>(Sb, T2, T1, nullptr, T3, w, lane, quad, l16);  // D2rh
  __syncthreads();
  gemmC_rm(T3, WcL, 5, w, lane, quad, l16, accc);          // c5 (D2rh)

  // final epilogue part 1: hn = u*h + (1-u)*c  (reads U; no Y/YT writes yet)
  const int o = w * 16 + l16;
  const float bias = bcL[o];
  float hn[8][4];
#pragma unroll
  for (int mt = 0; mt < 8; ++mt)
#pragma unroll
    for (int r = 0; r < 4; ++r) {
      const int m = mt * 16 + quad * 4 + r;
      const float cv = tanhf(accc[mt][r] + bias);
      const float uv = U[UIdx(m, o)];
      const float hv = hL[m * 128 + o];
      const float v = uv * hv + (1.f - uv) * cv;
      hn[mt][r] = v;
      hL[m * 128 + o] = v;
      const long base = (long)(b * 128 + m) * 128 + o;
      if (LAYER == 0) {
        if (t == 31) out[base] = v;
      } else {
        out[524288 + (long)t * 262144 + base] = v;
        if (t == 31) out[262144 + base] = v;
      }
    }
  __syncthreads();  // all U reads done before Y/YT (aliasing U) are written
  if (LAYER == 0) {
#pragma unroll
    for (int mt = 0; mt < 8; ++mt)
#pragma unroll
      for (int r = 0; r < 4; ++r) {
        const int m = mt * 16 + quad * 4 + r;
        const unsigned short hb = f2bf(hn[mt][r]);
        Y[BIdx(m, o)] = hb;   // layer1's x (rmaj)
        YT[BIdx(o, m)] = hb;  // layer1's xT
      }
  }
  __syncthreads();
}

__global__ void __launch_bounds__(NTHR, 2) dcgru(
    const float* __restrict__ inputs, const float* __restrict__ init_h,
    const float* __restrict__ sup,
    const float* __restrict__ Wg0, const float* __restrict__ bg0,
    const float* __restrict__ Wc0, const float* __restrict__ bc0,
    const float* __restrict__ Wg1, const float* __restrict__ bg1,
    const float* __restrict__ Wc1, const float* __restrict__ bc1,
    float* __restrict__ out, void* __restrict__ wsv) {
  __shared__ unsigned short T1[16384];   // 32 KB work tile
  __shared__ unsigned short T2[16384];   // 32 KB work tile
  __shared__ unsigned short T3[16384];   // 32 KB work tile
  __shared__ unsigned short Ybuf[32768]; // 64 KB: x/h handoff (Y+YT) | u (f32)
  unsigned short* Y = Ybuf;
  unsigned short* YT = Ybuf + 16384;
  float* U = (float*)Ybuf;

  unsigned* bar = (unsigned*)wsv;
  float* h_ws = (float*)wsv + 64;                          // [16][2][128][128]
  unsigned short* Sfr = (unsigned short*)(h_ws + 524288);  // [32][8][4][64][8]
  unsigned short* Wbg = Sfr + 524288;                      // [2][16][24][64][8]
  unsigned short* Wbc = Wbg + 393216;                      // [2][8][24][64][8]

  const int tid = threadIdx.x, bid = blockIdx.x;
  const int gtid = bid * NTHR + tid, gstride = GD * NTHR;
  const int lane = tid & 63, w = tid >> 6, quad = lane >> 4, l16 = lane & 15;
  const int b = bid;

  // ---- prep: h -> workspace; S/W fragment pre-arrangement (bf16) ----
  for (int i = tid; i < 32768; i += NTHR) {
    const int layer = i >> 14, j = i & 16383;
    h_ws[(long)(b * 2 + layer) * 16384 + j] = init_h[(long)(layer * 16 + b) * 16384 + j];
  }
  for (int idx = gtid; idx < 65536; idx += gstride) {  // S frags
    const int tt = idx >> 11, mt = (idx >> 8) & 7, ks = (idx >> 6) & 3, ln = idx & 63;
    const int m = mt * 16 + (ln & 15), k0 = ks * 32 + (ln >> 4) * 8;
    const float* src = sup + (long)tt * 16384 + m * 128 + k0;
    bf16x8 v;
#pragma unroll
    for (int j = 0; j < 8; j++) v[j] = (short)f2bf(src[j]);
    *(bf16x8*)(Sfr + (long)idx * 8) = v;
  }
  for (int idx = gtid; idx < 49152; idx += gstride) {  // Wg frags (2x16x24x64)
    const int l = idx / 24576;
    int rem = idx - l * 24576;
    const int ot = rem / 1536; rem -= ot * 1536;
    const int ks = rem >> 6, ln = rem & 63;
    const int o = ot * 16 + (ln & 15);
    const float* W = l ? Wg1 : Wg0;
    bf16x8 v;
#pragma unroll
    for (int j = 0; j < 8; j++) {
      const int kk = ks * 32 + (ln >> 4) * 8 + j;
      const int mm = kk >> 8, d = kk & 255;  // row reorder (d*3+mm) -> k
      v[j] = (short)f2bf(W[(d * 3 + mm) * 256 + o]);
    }
    *(bf16x8*)(Wbg + (long)idx * 8) = v;
  }
  for (int idx = gtid; idx < 24576; idx += gstride) {  // Wc frags (2x8x24x64)
    const int l = idx / 12288;
    int rem = idx - l * 12288;
    const int ot = rem / 1536; rem -= ot * 1536;
    const int ks = rem >> 6, ln = rem & 63;
    const int o = ot * 16 + (ln & 15);
    const float* W = l ? Wc1 : Wc0;
    bf16x8 v;
#pragma unroll
    for (int j = 0; j < 8; j++) {
      const int kk = ks * 32 + (ln >> 4) * 8 + j;
      const int mm = kk >> 8, d = kk & 255;
      v[j] = (short)f2bf(W[(d * 3 + mm) * 128 + o]);
    }
    *(bf16x8*)(Wbc + (long)idx * 8) = v;
  }
  grid_barrier(bar);  // one-time: frags visible to all blocks

  float* h0 = h_ws + (long)(b * 2 + 0) * 16384;
  float* h1 = h_ws + (long)(b * 2 + 1) * 16384;
  const unsigned short* Wg0f = Wbg;
  const unsigned short* Wg1f = Wbg + (long)16 * 24 * 512;
  const unsigned short* Wc0f = Wbc;
  const unsigned short* Wc1f = Wbc + (long)8 * 24 * 512;

  // ---- main loop: layer1 (t=s-1) first, then layer0 (t=s). No grid sync. ----
  for (int s = 0; s <= 32; ++s) {
    if (s >= 1)
      step<1>(s - 1, b, inputs, h1, Sfr + (long)(s - 1) * 16384, Wg1f, Wc1f,
              bg1, bc1, out, T1, T2, T3, Y, YT, U, tid, w, lane, quad, l16);
    if (s < 32)
      step<0>(s, b, inputs, h0, Sfr + (long)s * 16384, Wg0f, Wc0f,
              bg0, bc0, out, T1, T2, T3, Y, YT, U, tid, w, lane, quad, l16);
  }
}

extern "C" void kernel_launch(void* const* d_in, const int* in_sizes, int n_in,
                              void* d_out, int out_size, void* d_ws, size_t ws_size,
                              hipStream_t stream) {
  const float* inputs = (const float*)d_in[0];
  const float* init_h = (const float*)d_in[1];
  const float* sup    = (const float*)d_in[2];
  const float* Wg0 = (const float*)d_in[3];
  const float* bg0 = (const float*)d_in[4];
  const float* Wc0 = (const float*)d_in[5];
  const float* bc0 = (const float*)d_in[6];
  const float* Wg1 = (const float*)d_in[7];
  const float* bg1 = (const float*)d_in[8];
  const float* Wc1 = (const float*)d_in[9];
  const float* bc1 = (const float*)d_in[10];
  float* out = (float*)d_out;

  hipMemsetAsync(d_ws, 0, 256, stream);  // zero barrier state
  dcgru<<<GD, NTHR, 0, stream>>>(inputs, init_h, sup, Wg0, bg0, Wc0, bc0,
                                 Wg1, bg1, Wc1, bc1, out, d_ws);
}